// Round 13
// baseline (296.394 us; speedup 1.0000x reference)
//
#include <hip/hip_runtime.h>

#define SS 512
#define CC 128
#define RR (SS*SS)   // 262144

typedef unsigned short u16;
typedef unsigned int   u32;
typedef __attribute__((ext_vector_type(4))) float f32x4;
typedef __attribute__((ext_vector_type(8))) short s16x8;
typedef __attribute__((ext_vector_type(4))) u32   u32x4;

__device__ __forceinline__ float bf2f(u16 u){ u32 x = ((u32)u)<<16; float f; __builtin_memcpy(&f,&x,4); return f; }
__device__ __forceinline__ float sigf(float x){ return 1.f/(1.f + __expf(-x)); }

// HW packed f32->bf16 (RNE, identical bits to manual round-to-nearest-even)
__device__ __forceinline__ u32 cvtpk(float lo, float hi){
  u32 r; asm("v_cvt_pk_bf16_f32 %0, %1, %2" : "=v"(r) : "v"(lo), "v"(hi)); return r;
}

typedef __attribute__((address_space(1))) void* gptr_t;
typedef __attribute__((address_space(3))) void* lptr_t;
__device__ __forceinline__ void load_lds16(const void* g, void* l){
  __builtin_amdgcn_global_load_lds((gptr_t)(g), (lptr_t)(l), 16, 0, 0);
}

// ---------------------------------------------------------------------------
// K0: convert wa, wb, wg -> bf16 into d_out head (consumed by k1, safe);
//     wf -> bf16 into d_ws tail (consumed by k3 — must NOT live in d_out,
//     because k3 overwrites d_out while reading it; R10's NaN bug).
// ---------------------------------------------------------------------------
__global__ void k0(const float* __restrict__ wa, const float* __restrict__ wb,
                   const float* __restrict__ wg, const float* __restrict__ wf,
                   u16* __restrict__ wabg, u16* __restrict__ wfbg)
{
  int t = blockIdx.x*256 + threadIdx.x;      // 32 blocks -> 8192 threads, 8 elems each
  const float* srcs[4] = {wa, wb, wg, wf};
  int m = t >> 11;                            // 2048 threads per matrix
  int e = (t & 2047) * 8;
  const float* s = srcs[m] + e;
  u32 pk[4];
  #pragma unroll
  for (int v=0; v<2; v++){
    f32x4 x = *reinterpret_cast<const f32x4*>(s + v*4);
    pk[v*2]   = cvtpk(x[0], x[1]);
    pk[v*2+1] = cvtpk(x[2], x[3]);
  }
  u16* dst = (m==3) ? (wfbg + e) : (wabg + m*16384 + e);
  *reinterpret_cast<u32x4*>(dst) = *reinterpret_cast<u32x4*>(pk);
}

// ---------------------------------------------------------------------------
// K1: z -> LN -> { da=sig(zn@wa^T)-0.5 as a_t(c,r), db=sig(zn@wb^T)-0.5 as b_t(c,r),
//                  g=sig(zn@wg^T) as g(r,c) }  + SaPart[kblk][i][c] = sum_k da
// W staged in FOUR 32-row quarters (8 KB wk) -> 26 KB LDS -> 6 blocks/CU
// (24 waves, 75% occupancy cap). zn UNIONed with tr (16B-aligned; zn dead
// many barriers before the first tr write). All barriers plain __syncthreads
// (R12 A/B proved drain flavor neutral).
// ---------------------------------------------------------------------------
__global__ __launch_bounds__(256,6) void k1(
    const float* __restrict__ z, const float* __restrict__ lnw, const float* __restrict__ lnb,
    const u16* __restrict__ wabg,
    u16* __restrict__ a_t, u16* __restrict__ b_t, u16* __restrict__ g_out,
    float* __restrict__ SaPart)
{
  __shared__ __align__(16) u16 un[9216];      // union: zn[64][136] (8704) / tr[128][72] / gb[64][136]
  __shared__ __align__(16) u16 wk[32*128];    // QUARTER W matrix, XOR-swizzled (8 KB)
  u16 (*zn)[136] = reinterpret_cast<u16(*)[136]>(un);
  u16* tr = un;
  const int tid = threadIdx.x;
  const int r0  = blockIdx.x * 64;
  const int lane = tid & 63, w = tid >> 6;
  const int iI   = r0 >> 9;          // row index i (r = i*512 + k)
  const int kblk = (r0 >> 6) & 7;    // which 64-wide k block

  // stage W rows qt*32..qt*32+31 of matrix m; key (row&7) == (lr&7) since 32%8==0
  auto stageW = [&](int m, int qt){
    const u16* Wb = wabg + m*16384 + qt*4096;
    #pragma unroll
    for (int s=0;s<2;s++){
      int lr = s*16 + (tid>>4);
      const u16* gsrc = Wb + lr*128 + (((tid&15) ^ (lr&7))<<3);
      load_lds16((const void*)gsrc, (void*)&wk[s*2048 + w*512]);
    }
  };

  stageW(0,0);   // latency hides under LN

  // ---- LayerNorm: 4 threads per row ----
  {
    int row = tid >> 2, q = tid & 3;
    const float* src = z + (size_t)(r0+row)*CC + q*32;
    float v[32]; float s = 0.f, s2 = 0.f;
    #pragma unroll
    for (int i=0;i<8;i++){
      f32x4 t = *reinterpret_cast<const f32x4*>(src + i*4);
      #pragma unroll
      for (int e=0;e<4;e++){ float x = t[e]; v[i*4+e]=x; s += x; s2 += x*x; }
    }
    s  += __shfl_xor(s,1);  s2 += __shfl_xor(s2,1);
    s  += __shfl_xor(s,2);  s2 += __shfl_xor(s2,2);
    float mu  = s * (1.f/128.f);
    float var = s2*(1.f/128.f) - mu*mu;
    float rs  = rsqrtf(var + 1e-5f);
    #pragma unroll
    for (int i=0;i<4;i++){
      u32 pk[4];
      #pragma unroll
      for (int e=0;e<8;e+=2){
        int ci = i*8+e; int c = q*32 + ci;
        float y0 = (v[ci]  -mu)*rs*lnw[c]   + lnb[c];
        float y1 = (v[ci+1]-mu)*rs*lnw[c+1] + lnb[c+1];
        pk[e>>1] = cvtpk(y0, y1);
      }
      *reinterpret_cast<u32x4*>(&zn[row][q*32 + i*8]) = *reinterpret_cast<u32x4*>(pk);
    }
  }
  __syncthreads();   // zn visible AND stageW(0,0) drained (vmcnt 0)

  // A fragments: read once, reused for all three projections; every wave's
  // reads complete before its first-quarter MFMAs -> zn dead chip-wide many
  // barriers before the first tr write.
  s16x8 af[4];
  #pragma unroll
  for (int ks=0;ks<4;ks++)
    af[ks] = *reinterpret_cast<const s16x8*>(&zn[w*16 + (lane&15)][ks*32 + (lane>>4)*8]);

  for (int m=0;m<3;m++){
    f32x4 acc[8];
    #pragma unroll
    for (int cb=0;cb<8;cb++) acc[cb] = (f32x4){0.f,0.f,0.f,0.f};

    // ---- four quarters: wk holds W rows qt*32..qt*32+31 (out chans 2qt,2qt+1)
    for (int qt=0; qt<4; ++qt){
      __syncthreads();   // quarter (m,qt) resident (vmcnt drained)
      #pragma unroll
      for (int cc=0; cc<2; ++cc){
        int cb = qt*2 + cc;
        int lr = cc*16 + (lane&15);
        const int rx = (lr&7)<<3;
        const u16* base = &wk[lr*128];
        s16x8 b0 = *reinterpret_cast<const s16x8*>(&base[(  0 + (lane>>4)*8) ^ rx]);
        s16x8 b1 = *reinterpret_cast<const s16x8*>(&base[( 32 + (lane>>4)*8) ^ rx]);
        s16x8 b2 = *reinterpret_cast<const s16x8*>(&base[( 64 + (lane>>4)*8) ^ rx]);
        s16x8 b3 = *reinterpret_cast<const s16x8*>(&base[( 96 + (lane>>4)*8) ^ rx]);
        acc[cb] = __builtin_amdgcn_mfma_f32_16x16x32_bf16(af[0], b0, acc[cb], 0,0,0);
        acc[cb] = __builtin_amdgcn_mfma_f32_16x16x32_bf16(af[1], b1, acc[cb], 0,0,0);
        acc[cb] = __builtin_amdgcn_mfma_f32_16x16x32_bf16(af[2], b2, acc[cb], 0,0,0);
        acc[cb] = __builtin_amdgcn_mfma_f32_16x16x32_bf16(af[3], b3, acc[cb], 0,0,0);
      }
      __syncthreads();   // quarter reads done -> wk reusable
      if (qt<3) stageW(m, qt+1);
      // (next-m stage issued inside the epilogue, hidden under global stores)
    }

    if (m < 2){
      // centered: da = sigmoid - 0.5 -> bf16 (cvt_pk) -> LDS transpose [col][row]
      #pragma unroll
      for (int cb=0;cb<8;cb++){
        int col = cb*16 + (lane&15);
        int rbase = w*16 + (lane>>4)*4;
        u32 p0 = cvtpk(sigf(acc[cb][0])-0.5f, sigf(acc[cb][1])-0.5f);
        u32 p1 = cvtpk(sigf(acc[cb][2])-0.5f, sigf(acc[cb][3])-0.5f);
        u32* d = reinterpret_cast<u32*>(&tr[col*72 + rbase]);
        d[0] = p0; d[1] = p1;
      }
      __syncthreads();   // tr visible
      stageW(m+1, 0);    // issue next-m quarter 0; hides under global stores
      {
        int c = tid>>1, half = tid&1;
        u16* dst = (m==0 ? a_t : b_t) + ((size_t)c<<18) + r0 + half*32;
        const u16* srcl = &tr[c*72 + half*32];
        float s = 0.f;
        #pragma unroll
        for (int e=0;e<4;e++){
          u32x4 t = *reinterpret_cast<const u32x4*>(srcl + e*8);
          *reinterpret_cast<u32x4*>(dst + e*8) = t;
          #pragma unroll
          for (int q=0;q<4;q++){ u32 v = t[q]; s += bf2f((u16)v) + bf2f((u16)(v>>16)); }
        }
        if (m==0){
          s += __shfl_xor(s, 1);                 // combine halves (adjacent lanes)
          // layout [kblk][i][c]: 128 consecutive dwords per block -> coalesced
          if ((tid&1)==0) SaPart[(kblk<<16) + (iI<<7) + c] = s;
        }
      }
      __syncthreads();   // tr reads done (stage drained by next quarter-entry sync)
    } else {
      // g: stage [row][col] (stride 136) then coalesced row-major write
      u16* gb = &tr[0];
      #pragma unroll
      for (int cb=0;cb<8;cb++){
        int col = cb*16 + (lane&15);
        int rbase = w*16 + (lane>>4)*4;
        #pragma unroll
        for (int q=0;q<4;q++){
          float sg = sigf(acc[cb][q]);
          gb[(rbase+q)*136 + col] = (u16)cvtpk(sg, sg);
        }
      }
      __syncthreads();
      {
        int row = tid>>2, qo = tid&3;
        u16* dst = g_out + (size_t)(r0+row)*CC + qo*32;
        const u16* srcl = &gb[row*136 + qo*32];
        #pragma unroll
        for (int e=0;e<4;e++)
          *reinterpret_cast<u32x4*>(dst + e*8) = *reinterpret_cast<const u32x4*>(srcl + e*8);
      }
    }
  }
}

// ---------------------------------------------------------------------------
// K1b: b_t (c,k,j) -> bT (c,j,k) 64x64 LDS transpose + SbPart[c,j,kblk]=sum_k db
// ---------------------------------------------------------------------------
__global__ __launch_bounds__(256,8) void k1b(const u16* __restrict__ b_t, u16* __restrict__ bT,
                                             float* __restrict__ SbPart)
{
  __shared__ __align__(16) u16 tile[64][72];
  const int tid = threadIdx.x;
  const int c  = blockIdx.x >> 6;
  const int t  = blockIdx.x & 63;
  const int k0 = (t>>3)*64, j0 = (t&7)*64;
  const u16* src = b_t + ((size_t)c<<18);
  {
    int row = tid>>3, chunk = tid&7;
    #pragma unroll
    for (int pass=0; pass<2; pass++){
      int k = row + pass*32;
      const u16* s = src + (size_t)(k0+k)*SS + j0 + chunk*8;
      u32x4 v = *reinterpret_cast<const u32x4*>(s);
      int cs = chunk ^ ((k>>3)&7);
      *reinterpret_cast<u32x4*>(&tile[k][cs*8]) = v;
    }
  }
  __syncthreads();
  {
    int j = tid>>2, part = tid&3;
    u32 pk[8];
    float sb = 0.f;
    #pragma unroll
    for (int i=0;i<16;i+=2){
      int ka = part*16 + i;
      int key = (ka>>3)&7;
      u16 va = tile[ka  ][(((j>>3)^key)*8) + (j&7)];
      u16 vb = tile[ka+1][(((j>>3)^key)*8) + (j&7)];
      pk[i>>1] = (u32)va | ((u32)vb<<16);
      sb += bf2f(va) + bf2f(vb);
    }
    u16* dst = bT + ((size_t)c<<18) + (size_t)(j0+j)*SS + k0 + part*16;
    *reinterpret_cast<u32x4*>(dst)   = *reinterpret_cast<u32x4*>(pk);
    *reinterpret_cast<u32x4*>(dst+8) = *reinterpret_cast<u32x4*>(pk+4);
    sb += __shfl_xor(sb, 1);
    sb += __shfl_xor(sb, 2);
    if (part==0) SbPart[(((c<<9) + j0 + j)<<3) + (k0>>6)] = sb;
  }
}

// ---------------------------------------------------------------------------
// K1c: reduce partials -> Sa[c*512+i] (from [kblk][i][c]), Sb[c*512+j] (from [c][j][8])
// ---------------------------------------------------------------------------
__global__ void k1c(const float* __restrict__ SaPart, const float* __restrict__ SbPart,
                    float* __restrict__ Sa, float* __restrict__ Sb)
{
  int idx = blockIdx.x*256 + threadIdx.x;   // 0..131071
  if (idx < 65536){
    int i = idx >> 7, c = idx & 127;
    float s = 0.f;
    #pragma unroll
    for (int b=0;b<8;b++) s += SaPart[(b<<16) + (i<<7) + c];   // coalesced in c
    Sa[(c<<9) + i] = s;
  } else {
    int cj = idx & 65535;
    const float* src = SbPart + ((size_t)cj << 3);
    float s = 0.f;
    #pragma unroll
    for (int b=0;b<8;b++) s += src[b];
    Sb[cj] = s;
  }
}

// ---------------------------------------------------------------------------
// K2: per-channel GEMM  phat_c = 0.5*(Sa_i + Sb_j) + dA_c @ dB_c, stored fp16
// Flat grid 2048 with bijective XCD swizzle; 48 KB LDS -> 3 blocks/CU.
// ---------------------------------------------------------------------------
__global__ __launch_bounds__(256,3) void k2(const u16* __restrict__ a_t, const u16* __restrict__ bT,
                                            const float* __restrict__ Sa, const float* __restrict__ Sb,
                                            _Float16* __restrict__ ph)
{
  __shared__ __align__(16) u16 As[2][128*64];
  __shared__ __align__(16) u16 Bs[128*64];
  const int tid = threadIdx.x;
  const int lane = tid & 63, w = tid >> 6;
  const int bid = blockIdx.x;
  const int swz = (bid & 7) * 256 + (bid >> 3);   // bijective (2048 % 8 == 0)
  const int c   = swz >> 4;
  const int t16 = swz & 15;
  const int i0 = (t16 >> 2) * 128, j0 = (t16 & 3) * 128;
  const u16* Ag = a_t + ((size_t)c<<18);
  const u16* Bg = bT  + ((size_t)c<<18);
  const int pr = lane>>3, slot = lane&7;

  auto stageA = [&](int kt, int buf){
    #pragma unroll
    for (int s=0;s<4;s++){
      int rbase = w*32 + s*8;
      int rl = rbase + pr;
      const u16* g = Ag + (size_t)(i0+rl)*SS + kt*64 + ((slot^pr)*8);
      load_lds16((const void*)g, (void*)&As[buf][rbase*64]);
    }
  };
  auto stageB = [&](int kt){
    #pragma unroll
    for (int s=0;s<4;s++){
      int rbase = w*32 + s*8;
      int rl = rbase + pr;
      const u16* g = Bg + (size_t)(j0+rl)*SS + kt*64 + ((slot^pr)*8);
      load_lds16((const void*)g, (void*)&Bs[rbase*64]);
    }
  };

  f32x4 acc[4][4];
  #pragma unroll
  for (int a=0;a<4;a++)
    #pragma unroll
    for (int b=0;b<4;b++) acc[a][b] = (f32x4){0.f,0.f,0.f,0.f};
  const int wr = w>>1, wc = w&1;

  stageA(0, 0);
  for (int kt=0; kt<8; ++kt){
    stageB(kt);
    if (kt < 7){
      stageA(kt+1, (kt+1)&1);
      asm volatile("s_waitcnt vmcnt(4)" ::: "memory");
    } else {
      asm volatile("s_waitcnt vmcnt(0)" ::: "memory");
    }
    __builtin_amdgcn_s_barrier();
    const u16* Ab = &As[kt&1][0];
    #pragma unroll
    for (int ks=0;ks<2;ks++){
      s16x8 af[4], bfv[4];
      #pragma unroll
      for (int f=0; f<4; f++){
        int i = wr*64 + f*16 + (lane&15);
        int ch = (ks*4 + (lane>>4)) ^ (i&7);
        af[f] = *reinterpret_cast<const s16x8*>(&Ab[i*64 + ch*8]);
        int j = wc*64 + f*16 + (lane&15);
        int chb = (ks*4 + (lane>>4)) ^ (j&7);
        bfv[f] = *reinterpret_cast<const s16x8*>(&Bs[j*64 + chb*8]);
      }
      #pragma unroll
      for (int fi=0;fi<4;fi++)
        #pragma unroll
        for (int fj=0;fj<4;fj++)
          acc[fi][fj] = __builtin_amdgcn_mfma_f32_16x16x32_bf16(af[fi], bfv[fj], acc[fi][fj], 0,0,0);
    }
    asm volatile("s_waitcnt lgkmcnt(0)" ::: "memory");
    __builtin_amdgcn_s_barrier();
  }

  _Float16* P = ph + ((size_t)c<<18);
  const float* SaC = Sa + (c<<9);
  const float* SbC = Sb + (c<<9);
  float sbv[4];
  #pragma unroll
  for (int fj=0;fj<4;fj++) sbv[fj] = SbC[j0 + wc*64 + fj*16 + (lane&15)];
  #pragma unroll
  for (int fi=0;fi<4;fi++){
    int rbase = i0 + wr*64 + fi*16 + (lane>>4)*4;
    #pragma unroll
    for (int q=0;q<4;q++){
      float sav = SaC[rbase+q];
      #pragma unroll
      for (int fj=0;fj<4;fj++){
        int col = j0 + wc*64 + fj*16 + (lane&15);
        P[(size_t)(rbase+q)*SS + col] = (_Float16)(0.5f*(sav + sbv[fj]) + acc[fi][fj][q]);
      }
    }
  }
}

// ---------------------------------------------------------------------------
// K3: out[r][o] = g[r][o] * (LN_c(phat[. ,r]) @ wf^T)[o]   (phat = p-128, fp16)
// wf staged in TWO 64-row halves (16 KB wk) -> 35 KB LDS -> 4 blocks/CU.
// Per-acc accumulation order unchanged (ks ascending) -> bit-identical.
// ---------------------------------------------------------------------------
__global__ __launch_bounds__(256,4) void k3(const _Float16* __restrict__ ph, const u16* __restrict__ g,
    const float* __restrict__ flnw, const float* __restrict__ flnb,
    const u16* __restrict__ wfbg, float* __restrict__ out)
{
  __shared__ __align__(16) u16 znp[64][136];
  __shared__ __align__(16) u16 wk[64*128];
  __shared__ __align__(16) float red[4][64];
  __shared__ __align__(16) float muv[64], rsv[64];
  const int tid = threadIdx.x;
  const int rr0 = blockIdx.x * 64;
  const int lane = tid&63, w = tid>>6;
  const int pos = tid & 63, cq = tid >> 6;

  // stage wf rows h*64..h*64+63 (bf16, k0-converted) XOR-swizzled; 32%8==0 keeps key
  auto stageWF = [&](int h){
    const u16* Wb = wfbg + h*8192;
    #pragma unroll
    for (int s=0;s<4;s++){
      int lr = s*16 + (tid>>4);
      const u16* gsrc = Wb + lr*128 + (((tid&15) ^ (lr&7))<<3);
      load_lds16((const void*)gsrc, (void*)&wk[s*2048 + w*512]);
    }
  };

  stageWF(0);   // drained by the first __syncthreads below

  float pv[32];
  {
    const _Float16* src = ph + rr0 + pos;
    float s = 0.f;
    #pragma unroll
    for (int ci=0;ci<32;ci++){
      int c = cq*32 + ci;
      float x = (float)src[((size_t)c)<<18];
      pv[ci] = x; s += x;
    }
    red[cq][pos] = s;
  }
  __syncthreads();
  if (tid < 64) muv[tid] = (red[0][tid]+red[1][tid]+red[2][tid]+red[3][tid]) * (1.f/128.f);
  __syncthreads();
  float mu = muv[pos];
  {
    float s2 = 0.f;
    #pragma unroll
    for (int ci=0;ci<32;ci++){ float d = pv[ci]-mu; s2 += d*d; }
    red[cq][pos] = s2;
  }
  __syncthreads();
  if (tid < 64) rsv[tid] = rsqrtf((red[0][tid]+red[1][tid]+red[2][tid]+red[3][tid])*(1.f/128.f) + 1e-5f);
  __syncthreads();
  float rs = rsv[pos];
  {
    u32 pk[4];
    #pragma unroll
    for (int ii=0;ii<4;ii++){
      #pragma unroll
      for (int e=0;e<8;e+=2){
        int ci = ii*8+e; int c = cq*32+ci;
        float y0 = (pv[ci]  -mu)*rs*flnw[c]   + flnb[c];
        float y1 = (pv[ci+1]-mu)*rs*flnw[c+1] + flnb[c+1];
        pk[e>>1] = cvtpk(y0, y1);
      }
      *reinterpret_cast<u32x4*>(&znp[pos][cq*32 + ii*8]) = *reinterpret_cast<u32x4*>(pk);
    }
  }
  __syncthreads();

  f32x4 acc[8];
  #pragma unroll
  for (int cb=0;cb<8;cb++) acc[cb] = (f32x4){0.f,0.f,0.f,0.f};

  // ---- half 0: output channels 0..63 (wk holds wf rows 0..63) ----
  #pragma unroll
  for (int ks=0;ks<4;ks++){
    s16x8 af = *reinterpret_cast<const s16x8*>(&znp[w*16 + (lane&15)][ks*32 + (lane>>4)*8]);
    #pragma unroll
    for (int cb=0;cb<4;cb++){
      int lr = cb*16 + (lane&15);
      const int rx = (lr&7)<<3;
      s16x8 bf = *reinterpret_cast<const s16x8*>(&wk[lr*128 + ((ks*32 + (lane>>4)*8) ^ rx)]);
      acc[cb] = __builtin_amdgcn_mfma_f32_16x16x32_bf16(af, bf, acc[cb], 0,0,0);
    }
  }
  __syncthreads();     // half-0 reads done -> wk reusable
  stageWF(1);
  __syncthreads();     // half 1 resident (vmcnt drained)

  // ---- half 1: output channels 64..127 (wk holds wf rows 64..127) ----
  #pragma unroll
  for (int ks=0;ks<4;ks++){
    s16x8 af = *reinterpret_cast<const s16x8*>(&znp[w*16 + (lane&15)][ks*32 + (lane>>4)*8]);
    #pragma unroll
    for (int cb=4;cb<8;cb++){
      int lr = (cb-4)*16 + (lane&15);
      const int rx = (lr&7)<<3;
      s16x8 bf = *reinterpret_cast<const s16x8*>(&wk[lr*128 + ((ks*32 + (lane>>4)*8) ^ rx)]);
      acc[cb] = __builtin_amdgcn_mfma_f32_16x16x32_bf16(af, bf, acc[cb], 0,0,0);
    }
  }
  __syncthreads();   // znp reads done before overwrite with g

  // stage g tile into znp storage (reused), then multiply & write out
  u16* gb = &znp[0][0];
  {
    int row = tid>>2, qo = tid&3;
    const u16* src = g + (size_t)(rr0+row)*CC + qo*32;
    #pragma unroll
    for (int e=0;e<4;e++)
      *reinterpret_cast<u32x4*>(&gb[row*136 + qo*32 + e*8]) = *reinterpret_cast<const u32x4*>(src + e*8);
  }
  __syncthreads();
  #pragma unroll
  for (int cb=0;cb<8;cb++){
    int col = cb*16 + (lane&15);
    int rbase = w*16 + (lane>>4)*4;
    #pragma unroll
    for (int q=0;q<4;q++){
      float gv = bf2f(gb[(rbase+q)*136 + col]);
      out[(size_t)(rr0+rbase+q)*CC + col] = gv * acc[cb][q];
    }
  }
}

// ---------------------------------------------------------------------------
extern "C" void kernel_launch(void* const* d_in, const int* in_sizes, int n_in,
                              void* d_out, int out_size, void* d_ws, size_t ws_size,
                              hipStream_t stream)
{
  const float* z    = (const float*)d_in[0];
  const float* lnw  = (const float*)d_in[1];
  const float* lnb  = (const float*)d_in[2];
  const float* wa   = (const float*)d_in[3];
  const float* wb   = (const float*)d_in[4];
  const float* wg   = (const float*)d_in[5];
  const float* flnw = (const float*)d_in[6];
  const float* flnb = (const float*)d_in[7];
  const float* wf   = (const float*)d_in[8];
  float* out = (float*)d_out;

  char* ws = (char*)d_ws;
  u16* a_t = (u16*)(ws);                       // 64 MB  (c,i,k) bf16 (da)
  u16* bT  = (u16*)(ws + ((size_t)64<<20));    // 64 MB  (c,j,k) bf16 (db)
  u16* g   = (u16*)(ws + ((size_t)128<<20));   // 64 MB  (r,c)   bf16
  _Float16* ph = (_Float16*)(ws + ((size_t)192<<20)); // 64 MB (c,i,j) fp16 phat
  u16* b_t = (u16*)(ws + ((size_t)192<<20));   // 64 MB  (c,k,j) bf16 — aliases ph, dead before K2
  u16* wfbg = (u16*)(ws + ((size_t)256<<20));  // 32 KB  bf16 wf — in WS because K3 reads
                                               // it while writing d_out (R10 NaN bug)

  // scratch regions in d_out (all consumed BEFORE k3 writes out):
  char* ob = (char*)d_out;
  u16*   wabg   = (u16*)ob;                          // 96 KB  bf16 wa|wb|wg (read by k1)
  float* SaPart = (float*)(ob + ((size_t)1<<20));    // 2 MB   [kblk][i][c]  (read by k1c)
  float* SbPart = (float*)(ob + ((size_t)3<<20));    // 2 MB   [c][j][8]     (read by k1c)
  float* Sa     = (float*)(ob + ((size_t)5<<20));    // 256 KB [c][i]        (read by k2)
  float* Sb     = (float*)(ob + ((size_t)5<<20) + ((size_t)256<<10)); // 256 KB [c][j] (read by k2)

  k0 <<<32,   256, 0, stream>>>(wa, wb, wg, wf, wabg, wfbg);
  k1 <<<4096, 256, 0, stream>>>(z, lnw, lnb, wabg, a_t, b_t, g, SaPart);
  k1b<<<8192, 256, 0, stream>>>(b_t, bT, SbPart);
  k1c<<<512,  256, 0, stream>>>(SaPart, SbPart, Sa, Sb);
  k2 <<<2048, 256, 0, stream>>>(a_t, bT, Sa, Sb, ph);
  k3 <<<4096, 256, 0, stream>>>(ph, g, flnw, flnb, wfbg, out);
}

// Round 14
// 278.387 us; speedup vs baseline: 1.0647x; 1.0647x over previous
//
#include <hip/hip_runtime.h>

#define SS 512
#define CC 128
#define RR (SS*SS)   // 262144

typedef unsigned short u16;
typedef unsigned int   u32;
typedef __attribute__((ext_vector_type(4))) float f32x4;
typedef __attribute__((ext_vector_type(8))) short s16x8;
typedef __attribute__((ext_vector_type(4))) u32   u32x4;

__device__ __forceinline__ float bf2f(u16 u){ u32 x = ((u32)u)<<16; float f; __builtin_memcpy(&f,&x,4); return f; }
__device__ __forceinline__ float sigf(float x){ return 1.f/(1.f + __expf(-x)); }

// HW packed f32->bf16 (RNE, identical bits to manual round-to-nearest-even)
__device__ __forceinline__ u32 cvtpk(float lo, float hi){
  u32 r; asm("v_cvt_pk_bf16_f32 %0, %1, %2" : "=v"(r) : "v"(lo), "v"(hi)); return r;
}

typedef __attribute__((address_space(1))) void* gptr_t;
typedef __attribute__((address_space(3))) void* lptr_t;
__device__ __forceinline__ void load_lds16(const void* g, void* l){
  __builtin_amdgcn_global_load_lds((gptr_t)(g), (lptr_t)(l), 16, 0, 0);
}

// ---------------------------------------------------------------------------
// K0: convert wa, wb, wg -> bf16 into d_out head (consumed by k1, safe);
//     wf -> bf16 into d_ws tail (k3 reads it while writing d_out — R10 bug).
// ---------------------------------------------------------------------------
__global__ void k0(const float* __restrict__ wa, const float* __restrict__ wb,
                   const float* __restrict__ wg, const float* __restrict__ wf,
                   u16* __restrict__ wabg, u16* __restrict__ wfbg)
{
  int t = blockIdx.x*256 + threadIdx.x;      // 32 blocks -> 8192 threads, 8 elems each
  const float* srcs[4] = {wa, wb, wg, wf};
  int m = t >> 11;                            // 2048 threads per matrix
  int e = (t & 2047) * 8;
  const float* s = srcs[m] + e;
  u32 pk[4];
  #pragma unroll
  for (int v=0; v<2; v++){
    f32x4 x = *reinterpret_cast<const f32x4*>(s + v*4);
    pk[v*2]   = cvtpk(x[0], x[1]);
    pk[v*2+1] = cvtpk(x[2], x[3]);
  }
  u16* dst = (m==3) ? (wfbg + e) : (wabg + m*16384 + e);
  *reinterpret_cast<u32x4*>(dst) = *reinterpret_cast<u32x4*>(pk);
}

// ---------------------------------------------------------------------------
// K1: z -> LN -> { da=sig(zn@wa^T)-0.5 as a_t(c,r), db=sig(zn@wb^T)-0.5 as b_t(c,r),
//                  g=sig(zn@wg^T) as g(c,r) }  + SaPart[kblk][i][c] = sum_k da
// R11-proven config: 34 KB LDS, 4 blk/CU, VGPR 64 (R13's 6-blk cap spilled).
// ALL THREE epilogues now use the vectorized tr path (g stored (c,r) like a_t).
// ---------------------------------------------------------------------------
__global__ __launch_bounds__(256,4) void k1(
    const float* __restrict__ z, const float* __restrict__ lnw, const float* __restrict__ lnb,
    const u16* __restrict__ wabg,
    u16* __restrict__ a_t, u16* __restrict__ b_t, u16* __restrict__ g_out,
    float* __restrict__ SaPart)
{
  __shared__ __align__(16) u16 un[9216];      // union: zn[64][136] (8704) / tr[128][72]
  __shared__ __align__(16) u16 wk[64*128];    // HALF a W matrix, XOR-swizzled (16 KB)
  u16 (*zn)[136] = reinterpret_cast<u16(*)[136]>(un);
  u16* tr = un;
  const int tid = threadIdx.x;
  const int r0  = blockIdx.x * 64;
  const int lane = tid & 63, w = tid >> 6;
  const int iI   = r0 >> 9;          // row index i (r = i*512 + k)
  const int kblk = (r0 >> 6) & 7;    // which 64-wide k block

  // stage W rows h*64..h*64+63 of matrix m; key (row&7) == (lr&7) since 64%8==0
  auto stageW = [&](int m, int h){
    const u16* Wb = wabg + m*16384 + h*8192;
    #pragma unroll
    for (int s=0;s<4;s++){
      int lr = s*16 + (tid>>4);
      const u16* gsrc = Wb + lr*128 + (((tid&15) ^ (lr&7))<<3);
      load_lds16((const void*)gsrc, (void*)&wk[s*2048 + w*512]);
    }
  };

  stageW(0,0);   // latency hides under LN

  // ---- LayerNorm: 4 threads per row ----
  {
    int row = tid >> 2, q = tid & 3;
    const float* src = z + (size_t)(r0+row)*CC + q*32;
    float v[32]; float s = 0.f, s2 = 0.f;
    #pragma unroll
    for (int i=0;i<8;i++){
      f32x4 t = *reinterpret_cast<const f32x4*>(src + i*4);
      #pragma unroll
      for (int e=0;e<4;e++){ float x = t[e]; v[i*4+e]=x; s += x; s2 += x*x; }
    }
    s  += __shfl_xor(s,1);  s2 += __shfl_xor(s2,1);
    s  += __shfl_xor(s,2);  s2 += __shfl_xor(s2,2);
    float mu  = s * (1.f/128.f);
    float var = s2*(1.f/128.f) - mu*mu;
    float rs  = rsqrtf(var + 1e-5f);
    #pragma unroll
    for (int i=0;i<4;i++){
      u32 pk[4];
      #pragma unroll
      for (int e=0;e<8;e+=2){
        int ci = i*8+e; int c = q*32 + ci;
        float y0 = (v[ci]  -mu)*rs*lnw[c]   + lnb[c];
        float y1 = (v[ci+1]-mu)*rs*lnw[c+1] + lnb[c+1];
        pk[e>>1] = cvtpk(y0, y1);
      }
      *reinterpret_cast<u32x4*>(&zn[row][q*32 + i*8]) = *reinterpret_cast<u32x4*>(pk);
    }
  }
  __syncthreads();   // zn visible AND stageW(0,0) drained (vmcnt 0)

  // A fragments: read once, reused for all three projections; every wave's
  // reads complete before its half-0 MFMAs -> zn dead chip-wide before the
  // first tr write (3 barriers later).
  s16x8 af[4];
  #pragma unroll
  for (int ks=0;ks<4;ks++)
    af[ks] = *reinterpret_cast<const s16x8*>(&zn[w*16 + (lane&15)][ks*32 + (lane>>4)*8]);

  for (int m=0;m<3;m++){
    f32x4 acc[8];
    #pragma unroll
    for (int cb=0;cb<8;cb++) acc[cb] = (f32x4){0.f,0.f,0.f,0.f};

    // ---- half 0: output channels 0..63 (wk holds W rows 0..63) ----
    #pragma unroll
    for (int cb=0;cb<4;cb++){
      int lr = cb*16 + (lane&15);
      const int rx = (lr&7)<<3;
      const u16* base = &wk[lr*128];
      s16x8 b0 = *reinterpret_cast<const s16x8*>(&base[(  0 + (lane>>4)*8) ^ rx]);
      s16x8 b1 = *reinterpret_cast<const s16x8*>(&base[( 32 + (lane>>4)*8) ^ rx]);
      s16x8 b2 = *reinterpret_cast<const s16x8*>(&base[( 64 + (lane>>4)*8) ^ rx]);
      s16x8 b3 = *reinterpret_cast<const s16x8*>(&base[( 96 + (lane>>4)*8) ^ rx]);
      acc[cb] = __builtin_amdgcn_mfma_f32_16x16x32_bf16(af[0], b0, acc[cb], 0,0,0);
      acc[cb] = __builtin_amdgcn_mfma_f32_16x16x32_bf16(af[1], b1, acc[cb], 0,0,0);
      acc[cb] = __builtin_amdgcn_mfma_f32_16x16x32_bf16(af[2], b2, acc[cb], 0,0,0);
      acc[cb] = __builtin_amdgcn_mfma_f32_16x16x32_bf16(af[3], b3, acc[cb], 0,0,0);
    }
    __syncthreads();     // all reads of half 0 done
    stageW(m,1);
    __syncthreads();     // half 1 resident (vmcnt drained)

    // ---- half 1: output channels 64..127 (wk holds W rows 64..127) ----
    #pragma unroll
    for (int cb=4;cb<8;cb++){
      int lr = (cb-4)*16 + (lane&15);
      const int rx = (lr&7)<<3;
      const u16* base = &wk[lr*128];
      s16x8 b0 = *reinterpret_cast<const s16x8*>(&base[(  0 + (lane>>4)*8) ^ rx]);
      s16x8 b1 = *reinterpret_cast<const s16x8*>(&base[( 32 + (lane>>4)*8) ^ rx]);
      s16x8 b2 = *reinterpret_cast<const s16x8*>(&base[( 64 + (lane>>4)*8) ^ rx]);
      s16x8 b3 = *reinterpret_cast<const s16x8*>(&base[( 96 + (lane>>4)*8) ^ rx]);
      acc[cb] = __builtin_amdgcn_mfma_f32_16x16x32_bf16(af[0], b0, acc[cb], 0,0,0);
      acc[cb] = __builtin_amdgcn_mfma_f32_16x16x32_bf16(af[1], b1, acc[cb], 0,0,0);
      acc[cb] = __builtin_amdgcn_mfma_f32_16x16x32_bf16(af[2], b2, acc[cb], 0,0,0);
      acc[cb] = __builtin_amdgcn_mfma_f32_16x16x32_bf16(af[3], b3, acc[cb], 0,0,0);
    }
    __syncthreads();     // all reads of half 1 done -> wk free; zn dead (m=0)

    if (m<2) stageW(m+1,0);   // overlaps epilogue; drained by epilogue-final sync

    // ---- unified epilogue: value -> bf16 -> tr[col][row] -> (c,r) global ----
    {
      #pragma unroll
      for (int cb=0;cb<8;cb++){
        int col = cb*16 + (lane&15);
        int rbase = w*16 + (lane>>4)*4;
        u32 p0, p1;
        if (m < 2){
          p0 = cvtpk(sigf(acc[cb][0])-0.5f, sigf(acc[cb][1])-0.5f);
          p1 = cvtpk(sigf(acc[cb][2])-0.5f, sigf(acc[cb][3])-0.5f);
        } else {
          p0 = cvtpk(sigf(acc[cb][0]), sigf(acc[cb][1]));
          p1 = cvtpk(sigf(acc[cb][2]), sigf(acc[cb][3]));
        }
        u32* d = reinterpret_cast<u32*>(&tr[col*72 + rbase]);
        d[0] = p0; d[1] = p1;
      }
      __syncthreads();   // tr visible
      {
        int c = tid>>1, half = tid&1;
        u16* dst = (m==0 ? a_t : (m==1 ? b_t : g_out)) + ((size_t)c<<18) + r0 + half*32;
        const u16* srcl = &tr[c*72 + half*32];
        float s = 0.f;
        #pragma unroll
        for (int e=0;e<4;e++){
          u32x4 t = *reinterpret_cast<const u32x4*>(srcl + e*8);
          *reinterpret_cast<u32x4*>(dst + e*8) = t;
          if (m==0){
            #pragma unroll
            for (int q=0;q<4;q++){ u32 v = t[q]; s += bf2f((u16)v) + bf2f((u16)(v>>16)); }
          }
        }
        if (m==0){
          s += __shfl_xor(s, 1);                 // combine halves (adjacent lanes)
          if ((tid&1)==0) SaPart[(kblk<<16) + (iI<<7) + c] = s;
        }
      }
      if (m<2) __syncthreads();   // stageW(m+1,0) drained, tr reads done
    }
  }
}

// ---------------------------------------------------------------------------
// K1b: b_t (c,k,j) -> bT (c,j,k) 64x64 LDS transpose + SbPart[c,j,kblk]=sum_k db
// ---------------------------------------------------------------------------
__global__ __launch_bounds__(256,8) void k1b(const u16* __restrict__ b_t, u16* __restrict__ bT,
                                             float* __restrict__ SbPart)
{
  __shared__ __align__(16) u16 tile[64][72];
  const int tid = threadIdx.x;
  const int c  = blockIdx.x >> 6;
  const int t  = blockIdx.x & 63;
  const int k0 = (t>>3)*64, j0 = (t&7)*64;
  const u16* src = b_t + ((size_t)c<<18);
  {
    int row = tid>>3, chunk = tid&7;
    #pragma unroll
    for (int pass=0; pass<2; pass++){
      int k = row + pass*32;
      const u16* s = src + (size_t)(k0+k)*SS + j0 + chunk*8;
      u32x4 v = *reinterpret_cast<const u32x4*>(s);
      int cs = chunk ^ ((k>>3)&7);
      *reinterpret_cast<u32x4*>(&tile[k][cs*8]) = v;
    }
  }
  __syncthreads();
  {
    int j = tid>>2, part = tid&3;
    u32 pk[8];
    float sb = 0.f;
    #pragma unroll
    for (int i=0;i<16;i+=2){
      int ka = part*16 + i;
      int key = (ka>>3)&7;
      u16 va = tile[ka  ][(((j>>3)^key)*8) + (j&7)];
      u16 vb = tile[ka+1][(((j>>3)^key)*8) + (j&7)];
      pk[i>>1] = (u32)va | ((u32)vb<<16);
      sb += bf2f(va) + bf2f(vb);
    }
    u16* dst = bT + ((size_t)c<<18) + (size_t)(j0+j)*SS + k0 + part*16;
    *reinterpret_cast<u32x4*>(dst)   = *reinterpret_cast<u32x4*>(pk);
    *reinterpret_cast<u32x4*>(dst+8) = *reinterpret_cast<u32x4*>(pk+4);
    sb += __shfl_xor(sb, 1);
    sb += __shfl_xor(sb, 2);
    if (part==0) SbPart[(((c<<9) + j0 + j)<<3) + (k0>>6)] = sb;
  }
}

// ---------------------------------------------------------------------------
// K1c: reduce partials -> Sa[c*512+i] (from [kblk][i][c]), Sb[c*512+j] (from [c][j][8])
// ---------------------------------------------------------------------------
__global__ void k1c(const float* __restrict__ SaPart, const float* __restrict__ SbPart,
                    float* __restrict__ Sa, float* __restrict__ Sb)
{
  int idx = blockIdx.x*256 + threadIdx.x;   // 0..131071
  if (idx < 65536){
    int i = idx >> 7, c = idx & 127;
    float s = 0.f;
    #pragma unroll
    for (int b=0;b<8;b++) s += SaPart[(b<<16) + (i<<7) + c];   // coalesced in c
    Sa[(c<<9) + i] = s;
  } else {
    int cj = idx & 65535;
    const float* src = SbPart + ((size_t)cj << 3);
    float s = 0.f;
    #pragma unroll
    for (int b=0;b<8;b++) s += src[b];
    Sb[cj] = s;
  }
}

// ---------------------------------------------------------------------------
// K2: per-channel GEMM  phat_c = 0.5*(Sa_i + Sb_j) + dA_c @ dB_c, stored fp16
// Flat grid 2048 with bijective XCD swizzle; 48 KB LDS -> 3 blocks/CU.
// ---------------------------------------------------------------------------
__global__ __launch_bounds__(256,3) void k2(const u16* __restrict__ a_t, const u16* __restrict__ bT,
                                            const float* __restrict__ Sa, const float* __restrict__ Sb,
                                            _Float16* __restrict__ ph)
{
  __shared__ __align__(16) u16 As[2][128*64];
  __shared__ __align__(16) u16 Bs[128*64];
  const int tid = threadIdx.x;
  const int lane = tid & 63, w = tid >> 6;
  const int bid = blockIdx.x;
  const int swz = (bid & 7) * 256 + (bid >> 3);   // bijective (2048 % 8 == 0)
  const int c   = swz >> 4;
  const int t16 = swz & 15;
  const int i0 = (t16 >> 2) * 128, j0 = (t16 & 3) * 128;
  const u16* Ag = a_t + ((size_t)c<<18);
  const u16* Bg = bT  + ((size_t)c<<18);
  const int pr = lane>>3, slot = lane&7;

  auto stageA = [&](int kt, int buf){
    #pragma unroll
    for (int s=0;s<4;s++){
      int rbase = w*32 + s*8;
      int rl = rbase + pr;
      const u16* g = Ag + (size_t)(i0+rl)*SS + kt*64 + ((slot^pr)*8);
      load_lds16((const void*)g, (void*)&As[buf][rbase*64]);
    }
  };
  auto stageB = [&](int kt){
    #pragma unroll
    for (int s=0;s<4;s++){
      int rbase = w*32 + s*8;
      int rl = rbase + pr;
      const u16* g = Bg + (size_t)(j0+rl)*SS + kt*64 + ((slot^pr)*8);
      load_lds16((const void*)g, (void*)&Bs[rbase*64]);
    }
  };

  f32x4 acc[4][4];
  #pragma unroll
  for (int a=0;a<4;a++)
    #pragma unroll
    for (int b=0;b<4;b++) acc[a][b] = (f32x4){0.f,0.f,0.f,0.f};
  const int wr = w>>1, wc = w&1;

  stageA(0, 0);
  for (int kt=0; kt<8; ++kt){
    stageB(kt);
    if (kt < 7){
      stageA(kt+1, (kt+1)&1);
      asm volatile("s_waitcnt vmcnt(4)" ::: "memory");
    } else {
      asm volatile("s_waitcnt vmcnt(0)" ::: "memory");
    }
    __builtin_amdgcn_s_barrier();
    const u16* Ab = &As[kt&1][0];
    #pragma unroll
    for (int ks=0;ks<2;ks++){
      s16x8 af[4], bfv[4];
      #pragma unroll
      for (int f=0; f<4; f++){
        int i = wr*64 + f*16 + (lane&15);
        int ch = (ks*4 + (lane>>4)) ^ (i&7);
        af[f] = *reinterpret_cast<const s16x8*>(&Ab[i*64 + ch*8]);
        int j = wc*64 + f*16 + (lane&15);
        int chb = (ks*4 + (lane>>4)) ^ (j&7);
        bfv[f] = *reinterpret_cast<const s16x8*>(&Bs[j*64 + chb*8]);
      }
      #pragma unroll
      for (int fi=0;fi<4;fi++)
        #pragma unroll
        for (int fj=0;fj<4;fj++)
          acc[fi][fj] = __builtin_amdgcn_mfma_f32_16x16x32_bf16(af[fi], bfv[fj], acc[fi][fj], 0,0,0);
    }
    asm volatile("s_waitcnt lgkmcnt(0)" ::: "memory");
    __builtin_amdgcn_s_barrier();
  }

  _Float16* P = ph + ((size_t)c<<18);
  const float* SaC = Sa + (c<<9);
  const float* SbC = Sb + (c<<9);
  float sbv[4];
  #pragma unroll
  for (int fj=0;fj<4;fj++) sbv[fj] = SbC[j0 + wc*64 + fj*16 + (lane&15)];
  #pragma unroll
  for (int fi=0;fi<4;fi++){
    int rbase = i0 + wr*64 + fi*16 + (lane>>4)*4;
    #pragma unroll
    for (int q=0;q<4;q++){
      float sav = SaC[rbase+q];
      #pragma unroll
      for (int fj=0;fj<4;fj++){
        int col = j0 + wc*64 + fj*16 + (lane&15);
        P[(size_t)(rbase+q)*SS + col] = (_Float16)(0.5f*(sav + sbv[fj]) + acc[fi][fj][q]);
      }
    }
  }
}

// ---------------------------------------------------------------------------
// K3: out[r][o] = g[r][o] * (LN_c(phat[. ,r]) @ wf^T)[o]   (phat = p-128, fp16)
// g is (c,r): staged via u32x4 into tr-layout gb[c][72]; wf staged via
// global_load_lds XOR-swizzled (R11-proven). 53 KB LDS -> 3 blocks/CU.
// ---------------------------------------------------------------------------
__global__ __launch_bounds__(256,3) void k3(const _Float16* __restrict__ ph, const u16* __restrict__ g,
    const float* __restrict__ flnw, const float* __restrict__ flnb,
    const u16* __restrict__ wfbg, float* __restrict__ out)
{
  __shared__ __align__(16) u16 un[9216];     // union: znp[64][136] / gb[128][72]
  __shared__ __align__(16) u16 wk[128*128];
  __shared__ __align__(16) float red[4][64];
  __shared__ __align__(16) float muv[64], rsv[64];
  u16 (*znp)[136] = reinterpret_cast<u16(*)[136]>(un);
  const int tid = threadIdx.x;
  const int rr0 = blockIdx.x * 64;
  const int lane = tid&63, w = tid>>6;
  const int pos = tid & 63, cq = tid >> 6;

  // stage full wf (bf16) into XOR-swizzled wk; drained by the first __syncthreads
  {
    #pragma unroll
    for (int s=0;s<8;s++){
      int row = s*16 + (tid>>4);
      const u16* gsrc = wfbg + row*128 + (((tid&15) ^ (row&7))<<3);
      load_lds16((const void*)gsrc, (void*)&wk[s*2048 + w*512]);
    }
  }

  float pv[32];
  {
    const _Float16* src = ph + rr0 + pos;
    float s = 0.f;
    #pragma unroll
    for (int ci=0;ci<32;ci++){
      int c = cq*32 + ci;
      float x = (float)src[((size_t)c)<<18];
      pv[ci] = x; s += x;
    }
    red[cq][pos] = s;
  }
  __syncthreads();
  if (tid < 64) muv[tid] = (red[0][tid]+red[1][tid]+red[2][tid]+red[3][tid]) * (1.f/128.f);
  __syncthreads();
  float mu = muv[pos];
  {
    float s2 = 0.f;
    #pragma unroll
    for (int ci=0;ci<32;ci++){ float d = pv[ci]-mu; s2 += d*d; }
    red[cq][pos] = s2;
  }
  __syncthreads();
  if (tid < 64) rsv[tid] = rsqrtf((red[0][tid]+red[1][tid]+red[2][tid]+red[3][tid])*(1.f/128.f) + 1e-5f);
  __syncthreads();
  float rs = rsv[pos];
  {
    u32 pk[4];
    #pragma unroll
    for (int ii=0;ii<4;ii++){
      #pragma unroll
      for (int e=0;e<8;e+=2){
        int ci = ii*8+e; int c = cq*32+ci;
        float y0 = (pv[ci]  -mu)*rs*flnw[c]   + flnb[c];
        float y1 = (pv[ci+1]-mu)*rs*flnw[c+1] + flnb[c+1];
        pk[e>>1] = cvtpk(y0, y1);
      }
      *reinterpret_cast<u32x4*>(&znp[pos][cq*32 + ii*8]) = *reinterpret_cast<u32x4*>(pk);
    }
  }
  __syncthreads();

  f32x4 acc[8];
  #pragma unroll
  for (int cb=0;cb<8;cb++) acc[cb] = (f32x4){0.f,0.f,0.f,0.f};
  #pragma unroll
  for (int ks=0;ks<4;ks++){
    s16x8 af = *reinterpret_cast<const s16x8*>(&znp[w*16 + (lane&15)][ks*32 + (lane>>4)*8]);
    #pragma unroll
    for (int cb=0;cb<8;cb++){
      int row = cb*16 + (lane&15);
      const int rx = (row&7)<<3;
      s16x8 bf = *reinterpret_cast<const s16x8*>(&wk[row*128 + ((ks*32 + (lane>>4)*8) ^ rx)]);
      acc[cb] = __builtin_amdgcn_mfma_f32_16x16x32_bf16(af, bf, acc[cb], 0,0,0);
    }
  }
  __syncthreads();   // znp reads done before overwrite with g

  // stage g (c,r) tile into gb[c][72] (vectorized, same pattern as k1's write)
  u16* gb = un;
  {
    int c = tid>>1, half = tid&1;
    const u16* src = g + ((size_t)c<<18) + rr0 + half*32;
    u16* dstl = &gb[c*72 + half*32];
    #pragma unroll
    for (int e=0;e<4;e++)
      *reinterpret_cast<u32x4*>(dstl + e*8) = *reinterpret_cast<const u32x4*>(src + e*8);
  }
  __syncthreads();
  #pragma unroll
  for (int cb=0;cb<8;cb++){
    int col = cb*16 + (lane&15);
    int rbase = w*16 + (lane>>4)*4;
    #pragma unroll
    for (int q=0;q<4;q++){
      float gv = bf2f(gb[col*72 + rbase + q]);
      out[(size_t)(rr0+rbase+q)*CC + col] = gv * acc[cb][q];
    }
  }
}

// ---------------------------------------------------------------------------
extern "C" void kernel_launch(void* const* d_in, const int* in_sizes, int n_in,
                              void* d_out, int out_size, void* d_ws, size_t ws_size,
                              hipStream_t stream)
{
  const float* z    = (const float*)d_in[0];
  const float* lnw  = (const float*)d_in[1];
  const float* lnb  = (const float*)d_in[2];
  const float* wa   = (const float*)d_in[3];
  const float* wb   = (const float*)d_in[4];
  const float* wg   = (const float*)d_in[5];
  const float* flnw = (const float*)d_in[6];
  const float* flnb = (const float*)d_in[7];
  const float* wf   = (const float*)d_in[8];
  float* out = (float*)d_out;

  char* ws = (char*)d_ws;
  u16* a_t = (u16*)(ws);                       // 64 MB  (c,i,k) bf16 (da)
  u16* bT  = (u16*)(ws + ((size_t)64<<20));    // 64 MB  (c,j,k) bf16 (db)
  u16* g   = (u16*)(ws + ((size_t)128<<20));   // 64 MB  (c,r)   bf16
  _Float16* ph = (_Float16*)(ws + ((size_t)192<<20)); // 64 MB (c,i,j) fp16 phat
  u16* b_t = (u16*)(ws + ((size_t)192<<20));   // 64 MB  (c,k,j) bf16 — aliases ph, dead before K2
  u16* wfbg = (u16*)(ws + ((size_t)256<<20));  // 32 KB  bf16 wf — in WS because K3 reads
                                               // it while writing d_out (R10 NaN bug)

  // scratch regions in d_out (all consumed BEFORE k3 writes out):
  char* ob = (char*)d_out;
  u16*   wabg   = (u16*)ob;                          // 96 KB  bf16 wa|wb|wg (read by k1)
  float* SaPart = (float*)(ob + ((size_t)1<<20));    // 2 MB   [kblk][i][c]  (read by k1c)
  float* SbPart = (float*)(ob + ((size_t)3<<20));    // 2 MB   [c][j][8]     (read by k1c)
  float* Sa     = (float*)(ob + ((size_t)5<<20));    // 256 KB [c][i]        (read by k2)
  float* Sb     = (float*)(ob + ((size_t)5<<20) + ((size_t)256<<10)); // 256 KB [c][j] (read by k2)

  k0 <<<32,   256, 0, stream>>>(wa, wb, wg, wf, wabg, wfbg);
  k1 <<<4096, 256, 0, stream>>>(z, lnw, lnb, wabg, a_t, b_t, g, SaPart);
  k1b<<<8192, 256, 0, stream>>>(b_t, bT, SbPart);
  k1c<<<512,  256, 0, stream>>>(SaPart, SbPart, Sa, Sb);
  k2 <<<2048, 256, 0, stream>>>(a_t, bT, Sa, Sb, ph);
  k3 <<<4096, 256, 0, stream>>>(ph, g, flnw, flnb, wfbg, out);
}

// Round 15
// 276.411 us; speedup vs baseline: 1.0723x; 1.0072x over previous
//
#include <hip/hip_runtime.h>

#define SS 512
#define CC 128
#define RR (SS*SS)   // 262144

typedef unsigned short u16;
typedef unsigned int   u32;
typedef __attribute__((ext_vector_type(4))) float f32x4;
typedef __attribute__((ext_vector_type(8))) short s16x8;
typedef __attribute__((ext_vector_type(4))) u32   u32x4;

__device__ __forceinline__ float bf2f(u16 u){ u32 x = ((u32)u)<<16; float f; __builtin_memcpy(&f,&x,4); return f; }
__device__ __forceinline__ float sigf(float x){ return 1.f/(1.f + __expf(-x)); }

// HW packed f32->bf16 (RNE, identical bits to manual round-to-nearest-even)
__device__ __forceinline__ u32 cvtpk(float lo, float hi){
  u32 r; asm("v_cvt_pk_bf16_f32 %0, %1, %2" : "=v"(r) : "v"(lo), "v"(hi)); return r;
}

typedef __attribute__((address_space(1))) void* gptr_t;
typedef __attribute__((address_space(3))) void* lptr_t;
__device__ __forceinline__ void load_lds16(const void* g, void* l){
  __builtin_amdgcn_global_load_lds((gptr_t)(g), (lptr_t)(l), 16, 0, 0);
}

// ---------------------------------------------------------------------------
// K0: convert wa, wb, wg -> bf16 into d_out head (consumed by k1, safe);
//     wf -> bf16 into d_ws tail (k3 reads it while writing d_out — R10 bug).
// ---------------------------------------------------------------------------
__global__ void k0(const float* __restrict__ wa, const float* __restrict__ wb,
                   const float* __restrict__ wg, const float* __restrict__ wf,
                   u16* __restrict__ wabg, u16* __restrict__ wfbg)
{
  int t = blockIdx.x*256 + threadIdx.x;      // 32 blocks -> 8192 threads, 8 elems each
  const float* srcs[4] = {wa, wb, wg, wf};
  int m = t >> 11;                            // 2048 threads per matrix
  int e = (t & 2047) * 8;
  const float* s = srcs[m] + e;
  u32 pk[4];
  #pragma unroll
  for (int v=0; v<2; v++){
    f32x4 x = *reinterpret_cast<const f32x4*>(s + v*4);
    pk[v*2]   = cvtpk(x[0], x[1]);
    pk[v*2+1] = cvtpk(x[2], x[3]);
  }
  u16* dst = (m==3) ? (wfbg + e) : (wabg + m*16384 + e);
  *reinterpret_cast<u32x4*>(dst) = *reinterpret_cast<u32x4*>(pk);
}

// ---------------------------------------------------------------------------
// K1: z -> LN -> { da=sig(zn@wa^T)-0.5 as a_t(c,r), db=sig(zn@wb^T)-0.5 as b_t(c,r),
//                  g=sig(zn@wg^T) as g(c,r) }  + SaPart[kblk][i][c] = sum_k da
// W staged in FOUR 32-row quarters (8 KB wk) -> 26 KB LDS -> 6 blocks/CU by
// LDS. __launch_bounds__(256,4): allocator target stays 4 waves/EU (VGPR ~52,
// NO spill — R13's (256,6) cap caused 100 MB of scratch traffic); HW fills to
// 6 blocks since VGPR 52 allows 9 waves/SIMD.
// ---------------------------------------------------------------------------
__global__ __launch_bounds__(256,4) void k1(
    const float* __restrict__ z, const float* __restrict__ lnw, const float* __restrict__ lnb,
    const u16* __restrict__ wabg,
    u16* __restrict__ a_t, u16* __restrict__ b_t, u16* __restrict__ g_out,
    float* __restrict__ SaPart)
{
  __shared__ __align__(16) u16 un[9216];      // union: zn[64][136] (8704) / tr[128][72]
  __shared__ __align__(16) u16 wk[32*128];    // QUARTER W matrix, XOR-swizzled (8 KB)
  u16 (*zn)[136] = reinterpret_cast<u16(*)[136]>(un);
  u16* tr = un;
  const int tid = threadIdx.x;
  const int r0  = blockIdx.x * 64;
  const int lane = tid & 63, w = tid >> 6;
  const int iI   = r0 >> 9;          // row index i (r = i*512 + k)
  const int kblk = (r0 >> 6) & 7;    // which 64-wide k block

  // stage W rows qt*32..qt*32+31 of matrix m; key (row&7)==(lr&7) since 32%8==0
  auto stageW = [&](int m, int qt){
    const u16* Wb = wabg + m*16384 + qt*4096;
    #pragma unroll
    for (int s=0;s<2;s++){
      int lr = s*16 + (tid>>4);
      const u16* gsrc = Wb + lr*128 + (((tid&15) ^ (lr&7))<<3);
      load_lds16((const void*)gsrc, (void*)&wk[s*2048 + w*512]);
    }
  };

  stageW(0,0);   // latency hides under LN

  // ---- LayerNorm: 4 threads per row ----
  {
    int row = tid >> 2, q = tid & 3;
    const float* src = z + (size_t)(r0+row)*CC + q*32;
    float v[32]; float s = 0.f, s2 = 0.f;
    #pragma unroll
    for (int i=0;i<8;i++){
      f32x4 t = *reinterpret_cast<const f32x4*>(src + i*4);
      #pragma unroll
      for (int e=0;e<4;e++){ float x = t[e]; v[i*4+e]=x; s += x; s2 += x*x; }
    }
    s  += __shfl_xor(s,1);  s2 += __shfl_xor(s2,1);
    s  += __shfl_xor(s,2);  s2 += __shfl_xor(s2,2);
    float mu  = s * (1.f/128.f);
    float var = s2*(1.f/128.f) - mu*mu;
    float rs  = rsqrtf(var + 1e-5f);
    #pragma unroll
    for (int i=0;i<4;i++){
      u32 pk[4];
      #pragma unroll
      for (int e=0;e<8;e+=2){
        int ci = i*8+e; int c = q*32 + ci;
        float y0 = (v[ci]  -mu)*rs*lnw[c]   + lnb[c];
        float y1 = (v[ci+1]-mu)*rs*lnw[c+1] + lnb[c+1];
        pk[e>>1] = cvtpk(y0, y1);
      }
      *reinterpret_cast<u32x4*>(&zn[row][q*32 + i*8]) = *reinterpret_cast<u32x4*>(pk);
    }
  }
  __syncthreads();   // zn visible AND stageW(0,0) drained (vmcnt 0)

  // A fragments: read once, reused for all three projections; every wave's
  // reads complete before its first MFMAs -> zn dead chip-wide many barriers
  // before the first tr write.
  s16x8 af[4];
  #pragma unroll
  for (int ks=0;ks<4;ks++)
    af[ks] = *reinterpret_cast<const s16x8*>(&zn[w*16 + (lane&15)][ks*32 + (lane>>4)*8]);

  for (int m=0;m<3;m++){
    f32x4 acc[8];
    #pragma unroll
    for (int cb=0;cb<8;cb++) acc[cb] = (f32x4){0.f,0.f,0.f,0.f};

    // ---- four quarters: wk holds W rows qt*32..+31 (out chans cb=2qt,2qt+1)
    #pragma unroll
    for (int qt=0; qt<4; ++qt){
      __syncthreads();   // quarter (m,qt) resident (entry sync drains vmcnt)
      #pragma unroll
      for (int cc=0; cc<2; ++cc){
        int cb = qt*2 + cc;
        int lr = cc*16 + (lane&15);
        const int rx = (lr&7)<<3;
        const u16* base = &wk[lr*128];
        s16x8 b0 = *reinterpret_cast<const s16x8*>(&base[(  0 + (lane>>4)*8) ^ rx]);
        s16x8 b1 = *reinterpret_cast<const s16x8*>(&base[( 32 + (lane>>4)*8) ^ rx]);
        s16x8 b2 = *reinterpret_cast<const s16x8*>(&base[( 64 + (lane>>4)*8) ^ rx]);
        s16x8 b3 = *reinterpret_cast<const s16x8*>(&base[( 96 + (lane>>4)*8) ^ rx]);
        acc[cb] = __builtin_amdgcn_mfma_f32_16x16x32_bf16(af[0], b0, acc[cb], 0,0,0);
        acc[cb] = __builtin_amdgcn_mfma_f32_16x16x32_bf16(af[1], b1, acc[cb], 0,0,0);
        acc[cb] = __builtin_amdgcn_mfma_f32_16x16x32_bf16(af[2], b2, acc[cb], 0,0,0);
        acc[cb] = __builtin_amdgcn_mfma_f32_16x16x32_bf16(af[3], b3, acc[cb], 0,0,0);
      }
      __syncthreads();   // quarter reads done -> wk reusable
      if (qt<3) stageW(m, qt+1);   // drained by next qt's entry sync
    }

    if (m<2) stageW(m+1, 0);   // issue before epilogue; drained by next m's qt0 entry sync

    // ---- unified epilogue: value -> bf16 -> tr[col][row] -> (c,r) global ----
    {
      #pragma unroll
      for (int cb=0;cb<8;cb++){
        int col = cb*16 + (lane&15);
        int rbase = w*16 + (lane>>4)*4;
        u32 p0, p1;
        if (m < 2){
          p0 = cvtpk(sigf(acc[cb][0])-0.5f, sigf(acc[cb][1])-0.5f);
          p1 = cvtpk(sigf(acc[cb][2])-0.5f, sigf(acc[cb][3])-0.5f);
        } else {
          p0 = cvtpk(sigf(acc[cb][0]), sigf(acc[cb][1]));
          p1 = cvtpk(sigf(acc[cb][2]), sigf(acc[cb][3]));
        }
        u32* d = reinterpret_cast<u32*>(&tr[col*72 + rbase]);
        d[0] = p0; d[1] = p1;
      }
      __syncthreads();   // tr visible
      {
        int c = tid>>1, half = tid&1;
        u16* dst = (m==0 ? a_t : (m==1 ? b_t : g_out)) + ((size_t)c<<18) + r0 + half*32;
        const u16* srcl = &tr[c*72 + half*32];
        float s = 0.f;
        #pragma unroll
        for (int e=0;e<4;e++){
          u32x4 t = *reinterpret_cast<const u32x4*>(srcl + e*8);
          *reinterpret_cast<u32x4*>(dst + e*8) = t;
          if (m==0){
            #pragma unroll
            for (int q=0;q<4;q++){ u32 v = t[q]; s += bf2f((u16)v) + bf2f((u16)(v>>16)); }
          }
        }
        if (m==0){
          s += __shfl_xor(s, 1);                 // combine halves (adjacent lanes)
          if ((tid&1)==0) SaPart[(kblk<<16) + (iI<<7) + c] = s;
        }
      }
      if (m<2) __syncthreads();   // tr reads done before next m's tr writes
    }
  }
}

// ---------------------------------------------------------------------------
// K1b: b_t (c,k,j) -> bT (c,j,k) 64x64 LDS transpose + SbPart[c,j,kblk]=sum_k db
// ---------------------------------------------------------------------------
__global__ __launch_bounds__(256,8) void k1b(const u16* __restrict__ b_t, u16* __restrict__ bT,
                                             float* __restrict__ SbPart)
{
  __shared__ __align__(16) u16 tile[64][72];
  const int tid = threadIdx.x;
  const int c  = blockIdx.x >> 6;
  const int t  = blockIdx.x & 63;
  const int k0 = (t>>3)*64, j0 = (t&7)*64;
  const u16* src = b_t + ((size_t)c<<18);
  {
    int row = tid>>3, chunk = tid&7;
    #pragma unroll
    for (int pass=0; pass<2; pass++){
      int k = row + pass*32;
      const u16* s = src + (size_t)(k0+k)*SS + j0 + chunk*8;
      u32x4 v = *reinterpret_cast<const u32x4*>(s);
      int cs = chunk ^ ((k>>3)&7);
      *reinterpret_cast<u32x4*>(&tile[k][cs*8]) = v;
    }
  }
  __syncthreads();
  {
    int j = tid>>2, part = tid&3;
    u32 pk[8];
    float sb = 0.f;
    #pragma unroll
    for (int i=0;i<16;i+=2){
      int ka = part*16 + i;
      int key = (ka>>3)&7;
      u16 va = tile[ka  ][(((j>>3)^key)*8) + (j&7)];
      u16 vb = tile[ka+1][(((j>>3)^key)*8) + (j&7)];
      pk[i>>1] = (u32)va | ((u32)vb<<16);
      sb += bf2f(va) + bf2f(vb);
    }
    u16* dst = bT + ((size_t)c<<18) + (size_t)(j0+j)*SS + k0 + part*16;
    *reinterpret_cast<u32x4*>(dst)   = *reinterpret_cast<u32x4*>(pk);
    *reinterpret_cast<u32x4*>(dst+8) = *reinterpret_cast<u32x4*>(pk+4);
    sb += __shfl_xor(sb, 1);
    sb += __shfl_xor(sb, 2);
    if (part==0) SbPart[(((c<<9) + j0 + j)<<3) + (k0>>6)] = sb;
  }
}

// ---------------------------------------------------------------------------
// K1c: reduce partials -> Sa[c*512+i] (from [kblk][i][c]), Sb[c*512+j] (from [c][j][8])
// ---------------------------------------------------------------------------
__global__ void k1c(const float* __restrict__ SaPart, const float* __restrict__ SbPart,
                    float* __restrict__ Sa, float* __restrict__ Sb)
{
  int idx = blockIdx.x*256 + threadIdx.x;   // 0..131071
  if (idx < 65536){
    int i = idx >> 7, c = idx & 127;
    float s = 0.f;
    #pragma unroll
    for (int b=0;b<8;b++) s += SaPart[(b<<16) + (i<<7) + c];   // coalesced in c
    Sa[(c<<9) + i] = s;
  } else {
    int cj = idx & 65535;
    const float* src = SbPart + ((size_t)cj << 3);
    float s = 0.f;
    #pragma unroll
    for (int b=0;b<8;b++) s += src[b];
    Sb[cj] = s;
  }
}

// ---------------------------------------------------------------------------
// K2: per-channel GEMM  phat_c = 0.5*(Sa_i + Sb_j) + dA_c @ dB_c, stored fp16
// Flat grid 2048 with bijective XCD swizzle; 48 KB LDS -> 3 blocks/CU.
// ---------------------------------------------------------------------------
__global__ __launch_bounds__(256,3) void k2(const u16* __restrict__ a_t, const u16* __restrict__ bT,
                                            const float* __restrict__ Sa, const float* __restrict__ Sb,
                                            _Float16* __restrict__ ph)
{
  __shared__ __align__(16) u16 As[2][128*64];
  __shared__ __align__(16) u16 Bs[128*64];
  const int tid = threadIdx.x;
  const int lane = tid & 63, w = tid >> 6;
  const int bid = blockIdx.x;
  const int swz = (bid & 7) * 256 + (bid >> 3);   // bijective (2048 % 8 == 0)
  const int c   = swz >> 4;
  const int t16 = swz & 15;
  const int i0 = (t16 >> 2) * 128, j0 = (t16 & 3) * 128;
  const u16* Ag = a_t + ((size_t)c<<18);
  const u16* Bg = bT  + ((size_t)c<<18);
  const int pr = lane>>3, slot = lane&7;

  auto stageA = [&](int kt, int buf){
    #pragma unroll
    for (int s=0;s<4;s++){
      int rbase = w*32 + s*8;
      int rl = rbase + pr;
      const u16* g = Ag + (size_t)(i0+rl)*SS + kt*64 + ((slot^pr)*8);
      load_lds16((const void*)g, (void*)&As[buf][rbase*64]);
    }
  };
  auto stageB = [&](int kt){
    #pragma unroll
    for (int s=0;s<4;s++){
      int rbase = w*32 + s*8;
      int rl = rbase + pr;
      const u16* g = Bg + (size_t)(j0+rl)*SS + kt*64 + ((slot^pr)*8);
      load_lds16((const void*)g, (void*)&Bs[rbase*64]);
    }
  };

  f32x4 acc[4][4];
  #pragma unroll
  for (int a=0;a<4;a++)
    #pragma unroll
    for (int b=0;b<4;b++) acc[a][b] = (f32x4){0.f,0.f,0.f,0.f};
  const int wr = w>>1, wc = w&1;

  stageA(0, 0);
  for (int kt=0; kt<8; ++kt){
    stageB(kt);
    if (kt < 7){
      stageA(kt+1, (kt+1)&1);
      asm volatile("s_waitcnt vmcnt(4)" ::: "memory");
    } else {
      asm volatile("s_waitcnt vmcnt(0)" ::: "memory");
    }
    __builtin_amdgcn_s_barrier();
    const u16* Ab = &As[kt&1][0];
    #pragma unroll
    for (int ks=0;ks<2;ks++){
      s16x8 af[4], bfv[4];
      #pragma unroll
      for (int f=0; f<4; f++){
        int i = wr*64 + f*16 + (lane&15);
        int ch = (ks*4 + (lane>>4)) ^ (i&7);
        af[f] = *reinterpret_cast<const s16x8*>(&Ab[i*64 + ch*8]);
        int j = wc*64 + f*16 + (lane&15);
        int chb = (ks*4 + (lane>>4)) ^ (j&7);
        bfv[f] = *reinterpret_cast<const s16x8*>(&Bs[j*64 + chb*8]);
      }
      #pragma unroll
      for (int fi=0;fi<4;fi++)
        #pragma unroll
        for (int fj=0;fj<4;fj++)
          acc[fi][fj] = __builtin_amdgcn_mfma_f32_16x16x32_bf16(af[fi], bfv[fj], acc[fi][fj], 0,0,0);
    }
    asm volatile("s_waitcnt lgkmcnt(0)" ::: "memory");
    __builtin_amdgcn_s_barrier();
  }

  _Float16* P = ph + ((size_t)c<<18);
  const float* SaC = Sa + (c<<9);
  const float* SbC = Sb + (c<<9);
  float sbv[4];
  #pragma unroll
  for (int fj=0;fj<4;fj++) sbv[fj] = SbC[j0 + wc*64 + fj*16 + (lane&15)];
  #pragma unroll
  for (int fi=0;fi<4;fi++){
    int rbase = i0 + wr*64 + fi*16 + (lane>>4)*4;
    #pragma unroll
    for (int q=0;q<4;q++){
      float sav = SaC[rbase+q];
      #pragma unroll
      for (int fj=0;fj<4;fj++){
        int col = j0 + wc*64 + fj*16 + (lane&15);
        P[(size_t)(rbase+q)*SS + col] = (_Float16)(0.5f*(sav + sbv[fj]) + acc[fi][fj][q]);
      }
    }
  }
}

// ---------------------------------------------------------------------------
// K3: out[r][o] = g[r][o] * (LN_c(phat[. ,r]) @ wf^T)[o]   (phat = p-128, fp16)
// g is (c,r): staged via u32x4 into gb[c][72]; wf staged via global_load_lds
// XOR-swizzled. 53 KB LDS -> 3 blocks/CU.
// ---------------------------------------------------------------------------
__global__ __launch_bounds__(256,3) void k3(const _Float16* __restrict__ ph, const u16* __restrict__ g,
    const float* __restrict__ flnw, const float* __restrict__ flnb,
    const u16* __restrict__ wfbg, float* __restrict__ out)
{
  __shared__ __align__(16) u16 un[9216];     // union: znp[64][136] / gb[128][72]
  __shared__ __align__(16) u16 wk[128*128];
  __shared__ __align__(16) float red[4][64];
  __shared__ __align__(16) float muv[64], rsv[64];
  u16 (*znp)[136] = reinterpret_cast<u16(*)[136]>(un);
  const int tid = threadIdx.x;
  const int rr0 = blockIdx.x * 64;
  const int lane = tid&63, w = tid>>6;
  const int pos = tid & 63, cq = tid >> 6;

  // stage full wf (bf16) into XOR-swizzled wk; drained by the first __syncthreads
  {
    #pragma unroll
    for (int s=0;s<8;s++){
      int row = s*16 + (tid>>4);
      const u16* gsrc = wfbg + row*128 + (((tid&15) ^ (row&7))<<3);
      load_lds16((const void*)gsrc, (void*)&wk[s*2048 + w*512]);
    }
  }

  float pv[32];
  {
    const _Float16* src = ph + rr0 + pos;
    float s = 0.f;
    #pragma unroll
    for (int ci=0;ci<32;ci++){
      int c = cq*32 + ci;
      float x = (float)src[((size_t)c)<<18];
      pv[ci] = x; s += x;
    }
    red[cq][pos] = s;
  }
  __syncthreads();
  if (tid < 64) muv[tid] = (red[0][tid]+red[1][tid]+red[2][tid]+red[3][tid]) * (1.f/128.f);
  __syncthreads();
  float mu = muv[pos];
  {
    float s2 = 0.f;
    #pragma unroll
    for (int ci=0;ci<32;ci++){ float d = pv[ci]-mu; s2 += d*d; }
    red[cq][pos] = s2;
  }
  __syncthreads();
  if (tid < 64) rsv[tid] = rsqrtf((red[0][tid]+red[1][tid]+red[2][tid]+red[3][tid])*(1.f/128.f) + 1e-5f);
  __syncthreads();
  float rs = rsv[pos];
  {
    u32 pk[4];
    #pragma unroll
    for (int ii=0;ii<4;ii++){
      #pragma unroll
      for (int e=0;e<8;e+=2){
        int ci = ii*8+e; int c = cq*32+ci;
        float y0 = (pv[ci]  -mu)*rs*flnw[c]   + flnb[c];
        float y1 = (pv[ci+1]-mu)*rs*flnw[c+1] + flnb[c+1];
        pk[e>>1] = cvtpk(y0, y1);
      }
      *reinterpret_cast<u32x4*>(&znp[pos][cq*32 + ii*8]) = *reinterpret_cast<u32x4*>(pk);
    }
  }
  __syncthreads();

  f32x4 acc[8];
  #pragma unroll
  for (int cb=0;cb<8;cb++) acc[cb] = (f32x4){0.f,0.f,0.f,0.f};
  #pragma unroll
  for (int ks=0;ks<4;ks++){
    s16x8 af = *reinterpret_cast<const s16x8*>(&znp[w*16 + (lane&15)][ks*32 + (lane>>4)*8]);
    #pragma unroll
    for (int cb=0;cb<8;cb++){
      int row = cb*16 + (lane&15);
      const int rx = (row&7)<<3;
      s16x8 bf = *reinterpret_cast<const s16x8*>(&wk[row*128 + ((ks*32 + (lane>>4)*8) ^ rx)]);
      acc[cb] = __builtin_amdgcn_mfma_f32_16x16x32_bf16(af, bf, acc[cb], 0,0,0);
    }
  }
  __syncthreads();   // znp reads done before overwrite with g

  // stage g (c,r) tile into gb[c][72] (vectorized, same pattern as k1's write)
  u16* gb = un;
  {
    int c = tid>>1, half = tid&1;
    const u16* src = g + ((size_t)c<<18) + rr0 + half*32;
    u16* dstl = &gb[c*72 + half*32];
    #pragma unroll
    for (int e=0;e<4;e++)
      *reinterpret_cast<u32x4*>(dstl + e*8) = *reinterpret_cast<const u32x4*>(src + e*8);
  }
  __syncthreads();
  #pragma unroll
  for (int cb=0;cb<8;cb++){
    int col = cb*16 + (lane&15);
    int rbase = w*16 + (lane>>4)*4;
    #pragma unroll
    for (int q=0;q<4;q++){
      float gv = bf2f(gb[col*72 + rbase + q]);
      out[(size_t)(rr0+rbase+q)*CC + col] = gv * acc[cb][q];
    }
  }
}

// ---------------------------------------------------------------------------
extern "C" void kernel_launch(void* const* d_in, const int* in_sizes, int n_in,
                              void* d_out, int out_size, void* d_ws, size_t ws_size,
                              hipStream_t stream)
{
  const float* z    = (const float*)d_in[0];
  const float* lnw  = (const float*)d_in[1];
  const float* lnb  = (const float*)d_in[2];
  const float* wa   = (const float*)d_in[3];
  const float* wb   = (const float*)d_in[4];
  const float* wg   = (const float*)d_in[5];
  const float* flnw = (const float*)d_in[6];
  const float* flnb = (const float*)d_in[7];
  const float* wf   = (const float*)d_in[8];
  float* out = (float*)d_out;

  char* ws = (char*)d_ws;
  u16* a_t = (u16*)(ws);                       // 64 MB  (c,i,k) bf16 (da)
  u16* bT  = (u16*)(ws + ((size_t)64<<20));    // 64 MB  (c,j,k) bf16 (db)
  u16* g   = (u16*)(ws + ((size_t)128<<20));   // 64 MB  (c,r)   bf16
  _Float16* ph = (_Float16*)(ws + ((size_t)192<<20)); // 64 MB (c,i,j) fp16 phat
  u16* b_t = (u16*)(ws + ((size_t)192<<20));   // 64 MB  (c,k,j) bf16 — aliases ph, dead before K2
  u16* wfbg = (u16*)(ws + ((size_t)256<<20));  // 32 KB  bf16 wf — in WS because K3 reads
                                               // it while writing d_out (R10 NaN bug)

  // scratch regions in d_out (all consumed BEFORE k3 writes out):
  char* ob = (char*)d_out;
  u16*   wabg   = (u16*)ob;                          // 96 KB  bf16 wa|wb|wg (read by k1)
  float* SaPart = (float*)(ob + ((size_t)1<<20));    // 2 MB   [kblk][i][c]  (read by k1c)
  float* SbPart = (float*)(ob + ((size_t)3<<20));    // 2 MB   [c][j][8]     (read by k1c)
  float* Sa     = (float*)(ob + ((size_t)5<<20));    // 256 KB [c][i]        (read by k2)
  float* Sb     = (float*)(ob + ((size_t)5<<20) + ((size_t)256<<10)); // 256 KB [c][j] (read by k2)

  k0 <<<32,   256, 0, stream>>>(wa, wb, wg, wf, wabg, wfbg);
  k1 <<<4096, 256, 0, stream>>>(z, lnw, lnb, wabg, a_t, b_t, g, SaPart);
  k1b<<<8192, 256, 0, stream>>>(b_t, bT, SbPart);
  k1c<<<512,  256, 0, stream>>>(SaPart, SbPart, Sa, Sb);
  k2 <<<2048, 256, 0, stream>>>(a_t, bT, Sa, Sb, ph);
  k3 <<<4096, 256, 0, stream>>>(ph, g, flnw, flnb, wfbg, out);
}